// Round 4
// baseline (455.667 us; speedup 1.0000x reference)
//
#include <hip/hip_runtime.h>

// Emission-absorption volume renderer. fp32 in/out.
// Outputs flat: [features(3NR) | depths(NR) | opac(NR) | weights(128NR)].
//
// R8: persistent blocks + register double-buffered pipeline.
// Evidence: R4 (feats 3x line-amplified) and R7 (feats perfectly staged)
// run identical 130us / ~165MB FETCH / ~2TB/s -> NOT transaction-bound.
// VGPR stuck at 40 in both -> compiler serialized the loads; each wave
// pays full latency per load batch, then exits (one tile per wave).
// Fix: each block processes ~8 tiles; next tile's 13 loads are issued
// before computing the current tile, with launch_bounds(256,4) (128
// VGPR) so both register buffers fit. The vmcnt drain lands after the
// compute phase -> waves keep requests continuously outstanding.
//
// NUMERICAL NOTE (R3): the sample-127 sentinel delta (1e10) must NOT
// enter the prefix scan (fp32 cancellation corrupts absorption near ray
// end). It only feeds the final opacity, where exp(-~1e10) == 0.

#define BG_OPACITY_F 1e10f

typedef float floatx4 __attribute__((ext_vector_type(4)));

#define RSTRIDE 388   // LDS words per ray: 384 + 4 pad

__global__ __launch_bounds__(256, 4) void ea_render_kernel(
    const float* __restrict__ dens,    // (rays, 128)
    const float* __restrict__ feats,   // (rays, 128, 3)
    const float* __restrict__ lens,    // (rays, 128)
    const float* __restrict__ dirs,    // (rays, 3)
    float* __restrict__ out_feat,      // (rays, 3)
    float* __restrict__ out_depth,     // (rays)
    float* __restrict__ out_opac,      // (rays)
    float* __restrict__ out_w,         // (rays, 128)
    int n_rays)
{
    __shared__ __align__(16) float sfeat[16 * RSTRIDE];   // 24832 B

    const int tid  = threadIdx.x;
    const int lane = tid & 63;
    const int t    = lane & 15;                  // sub-lane within ray group
    const int rb   = tid >> 4;                   // ray index within tile 0..15
    const int n_tiles = (n_rays + 15) >> 4;

    // ---- double-buffered per-tile register state ----
    float4 fc[6],  nfc[6];                       // staged feats chunks
    float4 dA, dB, lA, lB, ndA, ndB, nlA, nlB;   // dens / lens
    float  dx, dy, dz, ndx, ndy, ndz;            // ray dir

    auto ISSUE = [&](long tk, float4* FC, float4& DA, float4& DB,
                     float4& LA, float4& LB,
                     float& DX, float& DY, float& DZ) {
        const long ray0 = tk << 4;
        const long ray  = (ray0 + rb < n_rays) ? (ray0 + rb) : (n_rays - 1);
        const long base = ray * 128;
        const int  n0   = t * 8;
        // block-coalesced feats chunks: 4KB contiguous per instruction
        #pragma unroll
        for (int k = 0; k < 6; ++k) {
            const int c = k * 256 + tid;         // 16B chunk id 0..1535
            long r = ray0 + c / 96;              // 96 chunks per ray
            if (r >= n_rays) r = n_rays - 1;
            FC[k] = *(const float4*)(feats + r * 384 + (long)(c % 96) * 4);
        }
        DA = *(const float4*)(dens + base + n0);
        DB = *(const float4*)(dens + base + n0 + 4);
        LA = *(const float4*)(lens + base + n0);
        LB = *(const float4*)(lens + base + n0 + 4);
        const float* dp = dirs + ray * 3;
        DX = dp[0]; DY = dp[1]; DZ = dp[2];
    };

    long tile = blockIdx.x;
    if (tile >= n_tiles) return;
    const long step = gridDim.x;

    ISSUE(tile, fc, dA, dB, lA, lB, dx, dy, dz);   // cold prologue

    for (; tile < n_tiles; tile += step) {
        // ---- land current tile's feats into LDS ----
        // chunk c -> ray r = c/96, lane t' = (c%96)/6, word i' = (c%96)%6
        #pragma unroll
        for (int k = 0; k < 6; ++k) {
            const int c   = k * 256 + tid;
            const int r   = c / 96;
            const int rem = c - r * 96;
            const int tq  = rem / 6;
            const int iq  = rem - tq * 6;
            *(float4*)&sfeat[r * RSTRIDE + tq * 24 + iq * 4] = fc[k];
        }
        __syncthreads();

        // ---- issue NEXT tile's loads; they fly during compute below ----
        const long next = tile + step;
        if (next < n_tiles)
            ISSUE(next, nfc, ndA, ndB, nlA, nlB, ndx, ndy, ndz);

        // ---- compute current tile ----
        const long ray0 = tile << 4;
        const long ray  = (ray0 + rb < n_rays) ? (ray0 + rb) : (n_rays - 1);
        const long base = ray * 128;
        const int  n0   = t * 8;

        const float dn = sqrtf(dx * dx + dy * dy + dz * dz);
        const float l[8]  = {lA.x, lA.y, lA.z, lA.w, lB.x, lB.y, lB.z, lB.w};
        const float dv[8] = {dA.x, dA.y, dA.z, dA.w, dB.x, dB.y, dB.z, dB.w};

        // l[0] of sub-lane t+1 (delta of our last sample). At t==15 this
        // crosses into the next ray's group - unused there (sentinel).
        const float lnext = __shfl_down(lA.x, 1, 64);

        float w[8];
        #pragma unroll
        for (int i = 0; i < 7; ++i)
            w[i] = (l[i + 1] - l[i]) * dn * fmaxf(dv[i], 0.0f);
        const float delta7 = (t == 15) ? BG_OPACITY_F : (lnext - l[7]);
        w[7] = delta7 * dn * fmaxf(dv[7], 0.0f);
        const float w7s = (t == 15) ? 0.0f : w[7];   // sentinel excluded

        const float s = w[0] + w[1] + w[2] + w[3] + w[4] + w[5] + w[6] + w7s;

        // 16-lane inclusive scan of per-lane sums (4 dependent steps)
        float inc = s;
        #pragma unroll
        for (int off = 1; off < 16; off <<= 1) {
            const float u = __shfl_up(inc, off, 64);
            if (t >= off) inc += u;              // t-mask keeps groups apart
        }
        const float excl = inc - s;              // sum over all n < n0

        // weights: wgt[i] = (1 - exp(-w[i])) * exp(-prefix_excl[i])
        float a = __expf(-excl);
        float wgt[8];
        #pragma unroll
        for (int i = 0; i < 8; ++i) {
            const float ei = __expf(-w[i]);      // t==15,i==7: exp(-1e10)=0
            wgt[i] = (1.0f - ei) * a;
            a *= ei;
        }

        // weights out (streamed, never re-read -> nontemporal)
        const floatx4 wv0 = {wgt[0], wgt[1], wgt[2], wgt[3]};
        const floatx4 wv1 = {wgt[4], wgt[5], wgt[6], wgt[7]};
        __builtin_nontemporal_store(wv0, (floatx4*)(out_w + base + n0));
        __builtin_nontemporal_store(wv1, (floatx4*)(out_w + base + n0 + 4));

        if (t == 15) {
            // inc == total real weighted; re-add sentinel for opacity.
            out_opac[ray] = 1.0f - __expf(-(inc + w[7]));
        }

        // per-lane feats from LDS: 6 x b128, contiguous 96B region
        const float* myf = &sfeat[rb * RSTRIDE + t * 24];
        const float4 q0 = *(const float4*)(myf +  0);
        const float4 q1 = *(const float4*)(myf +  4);
        const float4 q2 = *(const float4*)(myf +  8);
        const float4 q3 = *(const float4*)(myf + 12);
        const float4 q4 = *(const float4*)(myf + 16);
        const float4 q5 = *(const float4*)(myf + 20);

        float pd = 0.0f, fr = 0.0f, fg = 0.0f, fb = 0.0f;
        #pragma unroll
        for (int i = 0; i < 8; ++i) pd += wgt[i] * l[i];
        fr = wgt[0]*q0.x + wgt[1]*q0.w + wgt[2]*q1.z + wgt[3]*q2.y
           + wgt[4]*q3.x + wgt[5]*q3.w + wgt[6]*q4.z + wgt[7]*q5.y;
        fg = wgt[0]*q0.y + wgt[1]*q1.x + wgt[2]*q1.w + wgt[3]*q2.z
           + wgt[4]*q3.y + wgt[5]*q4.x + wgt[6]*q4.w + wgt[7]*q5.z;
        fb = wgt[0]*q0.z + wgt[1]*q1.y + wgt[2]*q2.x + wgt[3]*q2.w
           + wgt[4]*q3.z + wgt[5]*q4.y + wgt[6]*q5.x + wgt[7]*q5.w;

        // 16-lane butterfly reductions (xor stays within group)
        #pragma unroll
        for (int off = 8; off; off >>= 1) {
            pd += __shfl_xor(pd, off, 64);
            fr += __shfl_xor(fr, off, 64);
            fg += __shfl_xor(fg, off, 64);
            fb += __shfl_xor(fb, off, 64);
        }

        if (t == 0) {
            // features += (1 - opac) * BG_COLOR with BG_COLOR==0 -> no-op
            out_feat[ray * 3 + 0] = fr;
            out_feat[ray * 3 + 1] = fg;
            out_feat[ray * 3 + 2] = fb;
            out_depth[ray] = pd;
        }

        __syncthreads();                         // LDS safe to overwrite

        // ---- rotate buffers (forces the vmcnt drain HERE, post-compute) ----
        if (next < n_tiles) {
            #pragma unroll
            for (int k = 0; k < 6; ++k) fc[k] = nfc[k];
            dA = ndA; dB = ndB; lA = nlA; lB = nlB;
            dx = ndx; dy = ndy; dz = ndz;
        }
    }
}

extern "C" void kernel_launch(void* const* d_in, const int* in_sizes, int n_in,
                              void* d_out, int out_size, void* d_ws, size_t ws_size,
                              hipStream_t stream) {
    // Input order verified (R4 decode): dens(0), feats(1), lens(2), dirs(3).
    const float* dens  = (const float*)d_in[0];  // (B,R,N,1)
    const float* feats = (const float*)d_in[1];  // (B,R,N,3)
    const float* lens  = (const float*)d_in[2];  // (B,R,N)
    const float* dirs  = (const float*)d_in[3];  // (B,R,3)

    const int n_rays = in_sizes[3] / 3;          // B*R = 131072

    float* out = (float*)d_out;
    float* out_feat  = out;                       // (rays, 3)
    float* out_depth = out + (long)n_rays * 3;    // (rays, 1)
    float* out_opac  = out + (long)n_rays * 4;    // (rays, 1)
    float* out_w     = out + (long)n_rays * 5;    // (rays, 128)

    const int n_tiles = (n_rays + 15) / 16;       // 8192
    const int blocks  = n_tiles < 1024 ? n_tiles : 1024;  // persistent-ish
    ea_render_kernel<<<blocks, 256, 0, stream>>>(
        dens, feats, lens, dirs, out_feat, out_depth, out_opac, out_w, n_rays);
}

// Round 5
// 385.614 us; speedup vs baseline: 1.1817x; 1.1817x over previous
//
#include <hip/hip_runtime.h>

// Emission-absorption volume renderer. fp32 in/out.
// Outputs flat: [features(3NR) | depths(NR) | opac(NR) | weights(128NR)].
//
// R9: persistent blocks + 1-deep pipeline, spill-proof.
// R8 post-mortem: lambda took float4* into register arrays -> address-
// taken -> SCRATCH (VGPR=60, WRITE 443MB = spill traffic). But it proved
// 3.9 TB/s aggregate HBM through this kernel shape. This version:
//  - feats staged via __builtin_amdgcn_global_load_lds (6x 1KB DMA per
//    wave) into double-buffered LINEAR LDS (2 x 24576B). Zero VGPR cost,
//    perfectly coalesced, vmcnt-tracked; drained by the loop-top
//    __syncthreads after a full compute phase of latency cover.
//  - dens/lens/dirs prefetch in a by-value struct with NAMED members
//    (no arrays, no address taken -> SROA to registers).
//  - one barrier per tile; launch_bounds(256,3): LDS caps at 3 blk/CU
//    (2x24KB buffers), VGPR budget ample -> no spill.
//
// NUMERICAL NOTE (R3): the sample-127 sentinel delta (1e10) must NOT
// enter the prefix scan (fp32 cancellation corrupts absorption near ray
// end). It only feeds the final opacity, where exp(-~1e10) == 0.

#define BG_OPACITY_F 1e10f

typedef float floatx4 __attribute__((ext_vector_type(4)));

#define FEAT_WORDS (16 * 384)          // 6144 floats = 24576 B per buffer

struct Ray8 {                           // named members only -> SROA
    float4 dA, dB, lA, lB;
    float  dx, dy, dz;
};

__device__ __forceinline__ Ray8 load_ray(const float* __restrict__ dens,
                                         const float* __restrict__ lens,
                                         const float* __restrict__ dirs,
                                         long ray, int n0) {
    Ray8 r;
    const long base = ray * 128;
    r.dA = *(const float4*)(dens + base + n0);
    r.dB = *(const float4*)(dens + base + n0 + 4);
    r.lA = *(const float4*)(lens + base + n0);
    r.lB = *(const float4*)(lens + base + n0 + 4);
    const float* dp = dirs + ray * 3;
    r.dx = dp[0]; r.dy = dp[1]; r.dz = dp[2];
    return r;
}

// Stage one tile's feats (16 rays x 384 floats) global->LDS, linear
// layout (LDS word j == tile-local feats word j). Per wave-instruction:
// 64 lanes x 16B = 1KB contiguous; DMA, no VGPR destinations.
__device__ __forceinline__ void issue_feats(const float* __restrict__ feats,
                                            float* lbuf, long tile, int tid,
                                            int n_rays) {
    const long ray0 = tile << 4;
    const int  wave = tid >> 6;
    #pragma unroll
    for (int k = 0; k < 6; ++k) {
        const int c = k * 256 + tid;            // 16B chunk id 0..1535
        long r = ray0 + c / 96;                 // 96 chunks per ray
        if (r >= n_rays) r = n_rays - 1;        // tail clamp (consistent)
        const float* g = feats + r * 384 + (long)(c % 96) * 4;
        float* l = lbuf + (long)(k * 256 + wave * 64) * 4;  // wave-uniform
        __builtin_amdgcn_global_load_lds(
            (const __attribute__((address_space(1))) unsigned int*)g,
            (__attribute__((address_space(3))) unsigned int*)l, 16, 0, 0);
    }
}

__global__ __launch_bounds__(256, 3) void ea_render_kernel(
    const float* __restrict__ dens,    // (rays, 128)
    const float* __restrict__ feats,   // (rays, 128, 3)
    const float* __restrict__ lens,    // (rays, 128)
    const float* __restrict__ dirs,    // (rays, 3)
    float* __restrict__ out_feat,      // (rays, 3)
    float* __restrict__ out_depth,     // (rays)
    float* __restrict__ out_opac,      // (rays)
    float* __restrict__ out_w,         // (rays, 128)
    int n_rays)
{
    __shared__ __align__(16) float sfeat[2][FEAT_WORDS];   // 49152 B

    const int tid  = threadIdx.x;
    const int lane = tid & 63;
    const int t    = lane & 15;                  // sub-lane within ray group
    const int rb   = tid >> 4;                   // ray index within tile
    const int n0   = t * 8;                      // first sample owned
    const int n_tiles = (n_rays + 15) >> 4;
    const long step   = gridDim.x;

    long tile = blockIdx.x;
    if (tile >= n_tiles) return;                 // block-uniform

    // ---- prologue: tile 0 loads in flight ----
    {
        long ray = (tile << 4) + rb; if (ray >= n_rays) ray = n_rays - 1;
        issue_feats(feats, sfeat[0], tile, tid, n_rays);
    }
    long ray_c = (tile << 4) + rb; if (ray_c >= n_rays) ray_c = n_rays - 1;
    Ray8 cur = load_ray(dens, lens, dirs, ray_c, n0);
    Ray8 nxt = cur;
    int p = 0;

    for (; tile < n_tiles; tile += step, p ^= 1) {
        // Drains this wave's vmcnt (DMAs + prefetch loads) then syncs:
        // LDS[p] and `cur` are ready; loads had a full compute phase of
        // cover (except the prologue).
        __syncthreads();

        // ---- issue NEXT tile's loads; they fly during compute below ----
        const long next = tile + step;
        if (next < n_tiles) {
            issue_feats(feats, sfeat[p ^ 1], next, tid, n_rays);
            long rn = (next << 4) + rb; if (rn >= n_rays) rn = n_rays - 1;
            nxt = load_ray(dens, lens, dirs, rn, n0);
        }

        // ---- compute current tile ----
        long ray = (tile << 4) + rb; if (ray >= n_rays) ray = n_rays - 1;
        const long base = ray * 128;

        const float dn = sqrtf(cur.dx * cur.dx + cur.dy * cur.dy
                               + cur.dz * cur.dz);
        const float l[8]  = {cur.lA.x, cur.lA.y, cur.lA.z, cur.lA.w,
                             cur.lB.x, cur.lB.y, cur.lB.z, cur.lB.w};
        const float dv[8] = {cur.dA.x, cur.dA.y, cur.dA.z, cur.dA.w,
                             cur.dB.x, cur.dB.y, cur.dB.z, cur.dB.w};

        // l[0] of sub-lane t+1 (delta of our last sample). At t==15 this
        // crosses into the next ray's group - unused there (sentinel).
        const float lnext = __shfl_down(cur.lA.x, 1, 64);

        float w[8];
        #pragma unroll
        for (int i = 0; i < 7; ++i)
            w[i] = (l[i + 1] - l[i]) * dn * fmaxf(dv[i], 0.0f);
        const float delta7 = (t == 15) ? BG_OPACITY_F : (lnext - l[7]);
        w[7] = delta7 * dn * fmaxf(dv[7], 0.0f);
        const float w7s = (t == 15) ? 0.0f : w[7];   // sentinel excluded

        const float s = w[0] + w[1] + w[2] + w[3] + w[4] + w[5] + w[6] + w7s;

        // 16-lane inclusive scan of per-lane sums (4 dependent steps)
        float inc = s;
        #pragma unroll
        for (int off = 1; off < 16; off <<= 1) {
            const float u = __shfl_up(inc, off, 64);
            if (t >= off) inc += u;              // t-mask keeps groups apart
        }
        const float excl = inc - s;              // sum over all n < n0

        // weights: wgt[i] = (1 - exp(-w[i])) * exp(-prefix_excl[i])
        float a = __expf(-excl);
        float wgt[8];
        #pragma unroll
        for (int i = 0; i < 8; ++i) {
            const float ei = __expf(-w[i]);      // t==15,i==7: exp(-1e10)=0
            wgt[i] = (1.0f - ei) * a;
            a *= ei;
        }

        // weights out (streamed, never re-read -> nontemporal)
        const floatx4 wv0 = {wgt[0], wgt[1], wgt[2], wgt[3]};
        const floatx4 wv1 = {wgt[4], wgt[5], wgt[6], wgt[7]};
        __builtin_nontemporal_store(wv0, (floatx4*)(out_w + base + n0));
        __builtin_nontemporal_store(wv1, (floatx4*)(out_w + base + n0 + 4));

        if (t == 15) {
            // inc == total real weighted; re-add sentinel for opacity.
            out_opac[ray] = 1.0f - __expf(-(inc + w[7]));
        }

        // per-lane feats from LDS[p]: 6 x b128, contiguous 96B region
        const float* myf = &sfeat[p][rb * 384 + t * 24];
        const float4 q0 = *(const float4*)(myf +  0);
        const float4 q1 = *(const float4*)(myf +  4);
        const float4 q2 = *(const float4*)(myf +  8);
        const float4 q3 = *(const float4*)(myf + 12);
        const float4 q4 = *(const float4*)(myf + 16);
        const float4 q5 = *(const float4*)(myf + 20);

        float pd = 0.0f;
        #pragma unroll
        for (int i = 0; i < 8; ++i) pd += wgt[i] * l[i];
        float fr = wgt[0]*q0.x + wgt[1]*q0.w + wgt[2]*q1.z + wgt[3]*q2.y
                 + wgt[4]*q3.x + wgt[5]*q3.w + wgt[6]*q4.z + wgt[7]*q5.y;
        float fg = wgt[0]*q0.y + wgt[1]*q1.x + wgt[2]*q1.w + wgt[3]*q2.z
                 + wgt[4]*q3.y + wgt[5]*q4.x + wgt[6]*q4.w + wgt[7]*q5.z;
        float fb = wgt[0]*q0.z + wgt[1]*q1.y + wgt[2]*q2.x + wgt[3]*q2.w
                 + wgt[4]*q3.z + wgt[5]*q4.y + wgt[6]*q5.x + wgt[7]*q5.w;

        // 16-lane butterfly reductions (xor stays within group)
        #pragma unroll
        for (int off = 8; off; off >>= 1) {
            pd += __shfl_xor(pd, off, 64);
            fr += __shfl_xor(fr, off, 64);
            fg += __shfl_xor(fg, off, 64);
            fb += __shfl_xor(fb, off, 64);
        }

        if (t == 0) {
            // features += (1 - opac) * BG_COLOR with BG_COLOR==0 -> no-op
            out_feat[ray * 3 + 0] = fr;
            out_feat[ray * 3 + 1] = fg;
            out_feat[ray * 3 + 2] = fb;
            out_depth[ray] = pd;
        }

        cur = nxt;                               // register rotate (SROA)
    }
}

extern "C" void kernel_launch(void* const* d_in, const int* in_sizes, int n_in,
                              void* d_out, int out_size, void* d_ws, size_t ws_size,
                              hipStream_t stream) {
    // Input order verified (R4 decode): dens(0), feats(1), lens(2), dirs(3).
    const float* dens  = (const float*)d_in[0];  // (B,R,N,1)
    const float* feats = (const float*)d_in[1];  // (B,R,N,3)
    const float* lens  = (const float*)d_in[2];  // (B,R,N)
    const float* dirs  = (const float*)d_in[3];  // (B,R,3)

    const int n_rays = in_sizes[3] / 3;          // B*R = 131072

    float* out = (float*)d_out;
    float* out_feat  = out;                       // (rays, 3)
    float* out_depth = out + (long)n_rays * 3;    // (rays, 1)
    float* out_opac  = out + (long)n_rays * 4;    // (rays, 1)
    float* out_w     = out + (long)n_rays * 5;    // (rays, 128)

    const int n_tiles = (n_rays + 15) / 16;       // 8192
    // 3 blocks/CU x 256 CUs = 768 resident blocks; grid-stride the rest.
    const int blocks  = n_tiles < 768 ? n_tiles : 768;
    ea_render_kernel<<<blocks, 256, 0, stream>>>(
        dens, feats, lens, dirs, out_feat, out_depth, out_opac, out_w, n_rays);
}

// Round 6
// 383.162 us; speedup vs baseline: 1.1892x; 1.0064x over previous
//
#include <hip/hip_runtime.h>

// Emission-absorption volume renderer. fp32 in/out.
// Outputs flat: [features(3NR) | depths(NR) | opac(NR) | weights(128NR)].
//
// R10: max memory-level parallelism. Evidence across R4/R6/R7/R9: delivered
// bandwidth pinned at ~5.7 B/cy/CU (~3.2 TB/s) at occupancies 29-78% and
// four different staging schemes -> latency/concurrency-bound, with per-wave
// outstanding bytes never >~3KB (compiler serialized register-destination
// loads at VGPR 24-40; R9's DMA was occupancy-throttled). R8's spill traffic
// accidentally proved >=3.9 TB/s flows through this shape when more bytes
// are kept in flight.
// This version: one 64-thread block == one wave, NO barriers, NO LDS.
// 4 rays per wave as a pure ILP dimension: 32 VMEM loads (12.2 KB) issued
// back-to-back before any compute. launch_bounds(64,4) -> VGPR cap 128 so
// all load destinations stay live (the thing R6/R7 were denied). Issue
// order: dirs (wave-uniform -> s_load, off the vmcnt FIFO), dens/lens
// (consumed first), feats (consumed last) -> counted vmcnt waits drain in
// consumption order. Scan/butterfly interleaved across the 4 rays so the
// dependent ds_permute chains overlap.
//
// NUMERICAL NOTE (R3): the sample-127 sentinel delta (1e10) must NOT enter
// the prefix scan (fp32 cancellation corrupts absorption near the ray end).
// It only feeds the final opacity, where exp(-~1e10) == 0.

#define BG_OPACITY_F 1e10f

typedef float floatx2 __attribute__((ext_vector_type(2)));

__global__ __launch_bounds__(64, 4) void ea_render_kernel(
    const float* __restrict__ dens,    // (rays, 128)
    const float* __restrict__ feats,   // (rays, 128, 3)
    const float* __restrict__ lens,    // (rays, 128)
    const float* __restrict__ dirs,    // (rays, 3)
    float* __restrict__ out_feat,      // (rays, 3)
    float* __restrict__ out_depth,     // (rays)
    float* __restrict__ out_opac,      // (rays)
    float* __restrict__ out_w,         // (rays, 128)
    int n_rays)
{
    const int lane = threadIdx.x;                // block == one wave
    const long ray0 = (long)blockIdx.x * 4;
    if (ray0 >= n_rays) return;
    const int n0 = lane * 2;                     // samples n0, n0+1

    long ray[4];
    #pragma unroll
    for (int r = 0; r < 4; ++r) {
        const long q = ray0 + r;
        ray[r] = (q < n_rays) ? q : (n_rays - 1);  // tail clamp (benign dup)
    }

    // ---- issue ALL loads up front ------------------------------------
    // (1) dirs: wave-uniform address -> scalar loads (lgkmcnt, not vmcnt)
    float dxv[4], dyv[4], dzv[4];
    #pragma unroll
    for (int r = 0; r < 4; ++r) {
        const float* dp = dirs + ray[r] * 3;
        dxv[r] = dp[0]; dyv[r] = dp[1]; dzv[r] = dp[2];
    }
    // (2) dens/lens: consumed first, issued first among vector loads
    float2 d2[4], l2[4];
    #pragma unroll
    for (int r = 0; r < 4; ++r) {
        const long base = ray[r] * 128;
        d2[r] = *(const float2*)(dens + base + n0);
        l2[r] = *(const float2*)(lens + base + n0);
    }
    // (3) feats: consumed last -> stays in flight under all the math
    float2 f01[4], f23[4], f45[4];
    #pragma unroll
    for (int r = 0; r < 4; ++r) {
        const float* fp = feats + ray[r] * 384 + (long)n0 * 3;  // 8B aligned
        f01[r] = *(const float2*)(fp);
        f23[r] = *(const float2*)(fp + 2);
        f45[r] = *(const float2*)(fp + 4);
    }

    // ---- dir norms (waits only on the scalar dirs loads) -------------
    float dn[4];
    #pragma unroll
    for (int r = 0; r < 4; ++r)
        dn[r] = sqrtf(dxv[r]*dxv[r] + dyv[r]*dyv[r] + dzv[r]*dzv[r]);

    // ---- neighbor length (4 independent shuffles, pipelined) ---------
    float lnx[4];
    #pragma unroll
    for (int r = 0; r < 4; ++r)
        lnx[r] = __shfl_down(l2[r].x, 1, 64);    // lane l <- len[2l+2]

    // ---- weighted = delta * dir_norm * relu(dens) --------------------
    float w0[4], w1[4], s[4];
    #pragma unroll
    for (int r = 0; r < 4; ++r) {
        const float delta0 = l2[r].y - l2[r].x;
        const float delta1 = (lane == 63) ? BG_OPACITY_F : (lnx[r] - l2[r].y);
        w0[r] = delta0 * dn[r] * fmaxf(d2[r].x, 0.0f);
        w1[r] = delta1 * dn[r] * fmaxf(d2[r].y, 0.0f);
        const float w1s = (lane == 63) ? 0.0f : w1[r];   // sentinel excluded
        s[r] = w0[r] + w1s;
    }

    // ---- 64-lane inclusive scan, 4 rays interleaved (chains overlap) -
    float inc[4];
    #pragma unroll
    for (int r = 0; r < 4; ++r) inc[r] = s[r];
    #pragma unroll
    for (int off = 1; off < 64; off <<= 1) {
        #pragma unroll
        for (int r = 0; r < 4; ++r) {
            const float t = __shfl_up(inc[r], off, 64);
            if (lane >= off) inc[r] += t;
        }
    }

    // ---- weights + streamed stores + opacity -------------------------
    float wgt0[4], wgt1[4];
    #pragma unroll
    for (int r = 0; r < 4; ++r) {
        const float excl = inc[r] - s[r];        // sum over all n < n0
        const float e0 = __expf(-w0[r]);
        const float e1 = __expf(-w1[r]);         // lane63: exp(-~1e10) = 0
        const float a0 = __expf(-excl);
        const float a1 = a0 * e0;
        wgt0[r] = (1.0f - e0) * a0;
        wgt1[r] = (1.0f - e1) * a1;
        const floatx2 wv = {wgt0[r], wgt1[r]};
        __builtin_nontemporal_store(wv, (floatx2*)(out_w + ray[r] * 128 + n0));
        if (lane == 63) {
            // inc == total real weighted; re-add sentinel for opacity.
            out_opac[ray[r]] = 1.0f - __expf(-(inc[r] + w1[r]));
        }
    }

    // ---- per-lane partials (feats consumed here, after full cover) ---
    float pd[4], fr[4], fg[4], fb[4];
    #pragma unroll
    for (int r = 0; r < 4; ++r) {
        pd[r] = wgt0[r] * l2[r].x + wgt1[r] * l2[r].y;
        // sample n0: (f01.x, f01.y, f23.x); n0+1: (f23.y, f45.x, f45.y)
        fr[r] = wgt0[r] * f01[r].x + wgt1[r] * f23[r].y;
        fg[r] = wgt0[r] * f01[r].y + wgt1[r] * f45[r].x;
        fb[r] = wgt0[r] * f23[r].x + wgt1[r] * f45[r].y;
    }

    // ---- butterfly reductions, 16 values interleaved -----------------
    #pragma unroll
    for (int off = 32; off; off >>= 1) {
        #pragma unroll
        for (int r = 0; r < 4; ++r) {
            pd[r] += __shfl_xor(pd[r], off, 64);
            fr[r] += __shfl_xor(fr[r], off, 64);
            fg[r] += __shfl_xor(fg[r], off, 64);
            fb[r] += __shfl_xor(fb[r], off, 64);
        }
    }

    if (lane == 0) {
        #pragma unroll
        for (int r = 0; r < 4; ++r) {
            // features += (1 - opac) * BG_COLOR with BG_COLOR==0 -> no-op
            out_feat[ray[r] * 3 + 0] = fr[r];
            out_feat[ray[r] * 3 + 1] = fg[r];
            out_feat[ray[r] * 3 + 2] = fb[r];
            out_depth[ray[r]] = pd[r];
        }
    }
}

extern "C" void kernel_launch(void* const* d_in, const int* in_sizes, int n_in,
                              void* d_out, int out_size, void* d_ws, size_t ws_size,
                              hipStream_t stream) {
    // Input order verified (R4 decode): dens(0), feats(1), lens(2), dirs(3).
    const float* dens  = (const float*)d_in[0];  // (B,R,N,1)
    const float* feats = (const float*)d_in[1];  // (B,R,N,3)
    const float* lens  = (const float*)d_in[2];  // (B,R,N)
    const float* dirs  = (const float*)d_in[3];  // (B,R,3)

    const int n_rays = in_sizes[3] / 3;          // B*R = 131072

    float* out = (float*)d_out;
    float* out_feat  = out;                       // (rays, 3)
    float* out_depth = out + (long)n_rays * 3;    // (rays, 1)
    float* out_opac  = out + (long)n_rays * 4;    // (rays, 1)
    float* out_w     = out + (long)n_rays * 5;    // (rays, 128)

    const int blocks = (n_rays + 3) / 4;          // 1 wave / block, 4 rays
    ea_render_kernel<<<blocks, 64, 0, stream>>>(
        dens, feats, lens, dirs, out_feat, out_depth, out_opac, out_w, n_rays);
}